// Round 3
// baseline (240.162 us; speedup 1.0000x reference)
//
#include <hip/hip_runtime.h>
#include <hip/hip_bf16.h>

constexpr int kRows  = 4096;
constexpr int kCols  = 11008;
constexpr int kRank  = 32;

constexpr int RT     = 32;    // rows per block tile
constexpr int CT     = 256;   // cols per block tile (11008 = 43 * 256, exact)
constexpr int CP     = 264;   // corr LDS pitch in halfs (mult of 8 -> b128-aligned rows)

typedef __attribute__((ext_vector_type(8))) short    short8;  // 8 x bf16 MFMA frag
typedef __attribute__((ext_vector_type(4))) float    f32x4;   // MFMA accumulator
typedef __attribute__((ext_vector_type(8))) _Float16 half8;   // 16B corr read

__device__ __forceinline__ unsigned short bf16_rne(float x) {
    union { float f; unsigned u; } v; v.f = x;
    return (unsigned short)((v.u + 0x7FFFu + ((v.u >> 16) & 1u)) >> 16);
}

__global__ __launch_bounds__(256) void qw_fused(
    const float* __restrict__ codebooks,   // (2,256,8) fp32
    const int*   __restrict__ codes,       // flat 5,636,096 int32
    const float* __restrict__ scales,      // (11008,)
    const float* __restrict__ Lm,          // (4096,32)
    const float* __restrict__ Rm,          // (32,11008)
    float* __restrict__ outp)              // (4096,11008) fp32
{
    __shared__ __attribute__((aligned(16))) float    cb_lds[256 * 8];  // 8 KB: this block's codebook only
    __shared__ __attribute__((aligned(16))) _Float16 corr16[RT * CP];  // 16.9 KB fp16 low-rank corr tile

    const int tid = threadIdx.x;
    const int i0 = blockIdx.y * RT;
    const int j0 = blockIdx.x * CT;

    // cb index is BLOCK-UNIFORM: flat f >= Rows*Cols/2  <=>  global row >= 2048,
    // and i0 is a multiple of 32, so the whole tile uses one codebook.
    const int cb_flag = (i0 >= 2048) ? 1 : 0;

    // ---- prefetch phase-2 codes/scales (independent of LDS; hides under phase 1) ----
    const int g     = tid & 31;          // 8-col group within tile
    const int rbase = tid >> 5;          // 0..7
    int   cd[4];
    float sc[4];
    #pragma unroll
    for (int p = 0; p < 4; ++p) {
        const int row = rbase + (p << 3);
        const int f = (i0 + row) * kCols + j0 + (g << 3);
        cd[p] = codes[f >> 3];           // flat codes index == f/8 (exact: 11008%8==0)
        sc[p] = scales[f >> 12];         // scales broadcast along 4096-runs of flat idx
    }

    // ---- stage this block's codebook to LDS (2048 floats = 512 float4) ----
    {
        const float4* src = (const float4*)(codebooks + (cb_flag << 11));
        float4* dst = (float4*)cb_lds;
        dst[tid]       = src[tid];
        dst[tid + 256] = src[tid + 256];
    }

    // ---- phase 1: corr = L[i0:i0+32,:] @ R[:, j0:j0+256], one MFMA per 16x16 (K=32) ----
    {
        const int wave = tid >> 6;
        const int lane = tid & 63;
        const int n16  = lane & 15;       // m (A) / n (B) / col (C)
        const int q    = lane >> 4;       // quad
        const int kb   = q * 8;           // k-base for A/B frags

        // A frag: L[(i0 + (wave&1)*16 + m), kb..kb+7]
        const float* ap = Lm + (i0 + ((wave & 1) << 4) + n16) * kRank + kb;
        float4 a0 = *(const float4*)ap;
        float4 a1 = *(const float4*)(ap + 4);
        short8 af;
        af[0] = (short)bf16_rne(a0.x); af[1] = (short)bf16_rne(a0.y);
        af[2] = (short)bf16_rne(a0.z); af[3] = (short)bf16_rne(a0.w);
        af[4] = (short)bf16_rne(a1.x); af[5] = (short)bf16_rne(a1.y);
        af[6] = (short)bf16_rne(a1.z); af[7] = (short)bf16_rne(a1.w);

        const int row_base = ((wave & 1) << 4) + q * 4;   // C row = quad*4 + reg

        #pragma unroll
        for (int nt = 0; nt < 8; ++nt) {
            const int NT  = ((wave >> 1) << 3) + nt;      // n-subtile 0..15
            const int col = j0 + NT * 16 + n16;
            const float* bp = Rm + kb * kCols + col;      // B[k][n], 8 strided k (L2-hot)
            short8 bfr;
            #pragma unroll
            for (int t = 0; t < 8; ++t)
                bfr[t] = (short)bf16_rne(bp[t * kCols]);
            f32x4 acc = {0.f, 0.f, 0.f, 0.f};
            acc = __builtin_amdgcn_mfma_f32_16x16x32_bf16(af, bfr, acc, 0, 0, 0);
            const int ccol = NT * 16 + n16;
            #pragma unroll
            for (int r = 0; r < 4; ++r)
                corr16[(row_base + r) * CP + ccol] = (_Float16)acc[r];   // b16 writes, stride-1: free
        }
    }

    __syncthreads();

    // ---- phase 2: dequant gather + scale + corr add + fp32 store ----
    // 1 thread = one 8-col code group; half-wave stores 1KB contiguous per row segment.
    #pragma unroll
    for (int p = 0; p < 4; ++p) {
        const int row = rbase + (p << 3);
        const int f = (i0 + row) * kCols + j0 + (g << 3);
        const float scale = sc[p];
        const float* wsrc = cb_lds + (cd[p] << 3);
        const float4 w0 = *(const float4*)wsrc;
        const float4 w1 = *(const float4*)(wsrc + 4);
        const half8 ch = *(const half8*)(corr16 + row * CP + (g << 3));
        float4 o0, o1;
        o0.x = w0.x * scale + (float)ch[0];
        o0.y = w0.y * scale + (float)ch[1];
        o0.z = w0.z * scale + (float)ch[2];
        o0.w = w0.w * scale + (float)ch[3];
        o1.x = w1.x * scale + (float)ch[4];
        o1.y = w1.y * scale + (float)ch[5];
        o1.z = w1.z * scale + (float)ch[6];
        o1.w = w1.w * scale + (float)ch[7];
        *(float4*)(outp + f)     = o0;   // f % 8 == 0 -> 32B aligned
        *(float4*)(outp + f + 4) = o1;
    }
}

extern "C" void kernel_launch(void* const* d_in, const int* in_sizes, int n_in,
                              void* d_out, int out_size, void* d_ws, size_t ws_size,
                              hipStream_t stream) {
    const float* codebooks = (const float*)d_in[0];
    const int*   codes     = (const int*)d_in[1];
    const float* scales    = (const float*)d_in[2];
    const float* Lm        = (const float*)d_in[3];
    const float* Rm        = (const float*)d_in[4];
    float* outp            = (float*)d_out;

    dim3 grid(kCols / CT, kRows / RT);   // (43, 128), exact cover
    qw_fused<<<grid, dim3(256), 0, stream>>>(codebooks, codes, scales, Lm, Rm, outp);
}